// Round 6
// baseline (87.148 us; speedup 1.0000x reference)
//
#include <hip/hip_runtime.h>
#include <hip/hip_bf16.h>
#include <math.h>

#define B_ 8
#define T_ 256
#define LQ_ 20
#define LC_ 10
#define DIM_ 128
#define N_ 257            // T+1
#define NN_ (B_*N_)       // 2056

// ---------------- kAQ: video @ W_vproj split-K  ∪  query per-(b,lq) rows -----
__global__ __launch_bounds__(256) void kAQ(
    const float* __restrict__ video, const float* __restrict__ Wv,
    const int* __restrict__ word_ids, const int* __restrict__ char_ids,
    const float* __restrict__ word_emb, const float* __restrict__ char_emb,
    const float* __restrict__ W_embed, const float* __restrict__ b_embed,
    const float* __restrict__ We, const float* __restrict__ be,
    const float* __restrict__ q_mask,
    float* __restrict__ part, float* __restrict__ eq)
{
  __shared__ float smem[16 * 128];
  const int blk = blockIdx.x, tid = threadIdx.x;
  if (blk < 1024) {
    float (*Vl)[128] = reinterpret_cast<float(*)[128]>(smem);
    const int rt = blk & 127, ks = blk >> 7;
    const int r0 = rt * 16;
    for (int idx4 = tid; idx4 < 512; idx4 += 256) {
      const int i = idx4 >> 5, f = idx4 & 31;
      reinterpret_cast<float4*>(&Vl[i][0])[f] =
        reinterpret_cast<const float4*>(video + (size_t)(r0 + i) * 1024 + ks * 128)[f];
    }
    __syncthreads();
    const int jc = tid & 31, rg = tid >> 5;
    const int ra = rg * 2, rb = ra + 1;
    const float4* W4 = reinterpret_cast<const float4*>(Wv + (size_t)ks * 128 * 128) + jc;
    float4 a0 = {0,0,0,0}, a1 = {0,0,0,0};
    #pragma unroll 8
    for (int k = 0; k < 128; ++k) {
      const float4 w = W4[k * 32];
      const float x0 = Vl[ra][k], x1 = Vl[rb][k];
      a0.x += x0*w.x; a0.y += x0*w.y; a0.z += x0*w.z; a0.w += x0*w.w;
      a1.x += x1*w.x; a1.y += x1*w.y; a1.z += x1*w.z; a1.w += x1*w.w;
    }
    *reinterpret_cast<float4*>(part + (((size_t)ks * 2048) + r0 + ra) * 128 + 4 * jc) = a0;
    *reinterpret_cast<float4*>(part + (((size_t)ks * 2048) + r0 + rb) * 128 + 4 * jc) = a1;
  } else {
    const int qi = blk - 1024;
    const int b = qi / 20, lq = qi - b * 20;
    float* emb = smem;            // [352]
    float* ps  = smem + 352;      // [2][128]
    float* hl  = smem + 608;      // [128]
    float* pe  = smem + 736;      // [2][128]
    const int wid = word_ids[b * LQ_ + lq];
    for (int m = tid; m < 300; m += 256) emb[m] = word_emb[(size_t)wid * 300 + m];
    if (tid < 50) {
      float s = 0.f;
      #pragma unroll
      for (int l = 0; l < 10; ++l) {
        const int cid = char_ids[(b * LQ_ + lq) * 10 + l];
        s += char_emb[cid * 50 + tid];
      }
      emb[300 + tid] = s * 0.1f;
    }
    __syncthreads();
    const int j = tid & 127, half = tid >> 7;
    float a = 0.f;
    const float* Wcol = W_embed + (size_t)(half * 175) * 128 + j;
    const float* eh = emb + half * 175;
    #pragma unroll 5
    for (int m = 0; m < 175; ++m) a += eh[m] * Wcol[(size_t)m * 128];
    ps[half * 128 + j] = a;
    __syncthreads();
    if (tid < 128) hl[tid] = ps[tid] + ps[128 + tid] + b_embed[tid];
    __syncthreads();
    float e = 0.f;
    #pragma unroll 8
    for (int kk = 0; kk < 64; ++kk)
      e += hl[half * 64 + kk] * We[(half * 64 + kk) * 128 + j];
    pe[half * 128 + j] = e;
    __syncthreads();
    if (tid < 128) {
      float ev = pe[tid] + pe[128 + tid] + be[tid];
      ev = fmaxf(ev, 0.f) * q_mask[b * LQ_ + lq];
      eq[(size_t)qi * 128 + tid] = ev;
    }
  }
}

// ---------------- kBR3: 8-row blocks: part-reduce + enc + fused projections --
// blocks 0..255: 8 video rows; blocks 256..263: query mean + node-0 proj.
// xf is never consumed downstream -> not written at all.
__global__ __launch_bounds__(256) void kBR3(
    const float* __restrict__ part, const float* __restrict__ bvp,
    const float* __restrict__ We, const float* __restrict__ be,
    const float* __restrict__ vmask, const float* __restrict__ eq,
    const float* __restrict__ Wq, const float* __restrict__ bq,
    const float* __restrict__ Wk, const float* __restrict__ bk,
    const float* __restrict__ Wvv, const float* __restrict__ bval,
    const float* __restrict__ Ws, const float* __restrict__ bs,
    float* __restrict__ q, float* __restrict__ k,
    float* __restrict__ v, float* __restrict__ sk)
{
  __shared__ float h[8][128];
  __shared__ float xe[8][132];     // pad 132: bank-spread, 16B-aligned rows
  const int blk = blockIdx.x, tid = threadIdx.x;
  const float* Wm[4] = {Wq, Wk, Wvv, Ws};
  const float* bm[4] = {bq, bk, bval, bs};
  float* om[4] = {q, k, v, sk};
  if (blk < 256) {
    const int col = tid & 127, rh = tid >> 7;
    const int r0 = blk * 8;
    #pragma unroll
    for (int rr = 0; rr < 4; ++rr) {
      const int row = rr * 2 + rh;
      float s = bvp[col];
      #pragma unroll
      for (int ks = 0; ks < 8; ++ks)
        s += part[((size_t)ks * 2048 + r0 + row) * 128 + col];
      h[row][col] = s;
    }
    __syncthreads();
    // enc: thread (jc = 4 cols, rg = row)
    const int jc = tid & 31, rg = tid >> 5;
    {
      const float4* We4 = reinterpret_cast<const float4*>(We) + jc;
      float4 a = reinterpret_cast<const float4*>(be)[jc];
      #pragma unroll 8
      for (int kk = 0; kk < 128; ++kk) {
        const float4 w = We4[kk * 32];
        const float x = h[rg][kk];
        a.x += x*w.x; a.y += x*w.y; a.z += x*w.z; a.w += x*w.w;
      }
      const float mk = vmask[r0 + rg];
      a.x = fmaxf(a.x, 0.f) * mk; a.y = fmaxf(a.y, 0.f) * mk;
      a.z = fmaxf(a.z, 0.f) * mk; a.w = fmaxf(a.w, 0.f) * mk;
      *reinterpret_cast<float4*>(&xe[rg][4 * jc]) = a;
    }
    __syncthreads();
    // proj: thread (jc, m = rg&3, g = rg>>2) -> rows 4g..4g+3, 16 FMA/W-load
    const int m = rg & 3, g = rg >> 2;
    const float4* W4p = reinterpret_cast<const float4*>(Wm[m]) + jc;
    const float4 bb = reinterpret_cast<const float4*>(bm[m])[jc];
    float4 ac0 = bb, ac1 = bb, ac2 = bb, ac3 = bb;
    #pragma unroll 4
    for (int kk = 0; kk < 128; ++kk) {
      const float4 w = W4p[kk * 32];
      const float x0 = xe[4*g+0][kk], x1 = xe[4*g+1][kk];
      const float x2 = xe[4*g+2][kk], x3 = xe[4*g+3][kk];
      ac0.x += x0*w.x; ac0.y += x0*w.y; ac0.z += x0*w.z; ac0.w += x0*w.w;
      ac1.x += x1*w.x; ac1.y += x1*w.y; ac1.z += x1*w.z; ac1.w += x1*w.w;
      ac2.x += x2*w.x; ac2.y += x2*w.y; ac2.z += x2*w.z; ac2.w += x2*w.w;
      ac3.x += x3*w.x; ac3.y += x3*w.y; ac3.z += x3*w.z; ac3.w += x3*w.w;
    }
    float4 acs[4] = {ac0, ac1, ac2, ac3};
    #pragma unroll
    for (int r = 0; r < 4; ++r) {
      const int vr = r0 + 4 * g + r;
      const int node = (vr >> 8) * 257 + 1 + (vr & 255);
      *reinterpret_cast<float4*>(om[m] + (size_t)node * 128 + 4 * jc) = acs[r];
    }
  } else {
    const int b = blk - 256;
    if (tid < 128) {
      float s = 0.f;
      #pragma unroll 4
      for (int lq = 0; lq < LQ_; ++lq) s += eq[((size_t)b * LQ_ + lq) * 128 + tid];
      xe[0][tid] = s * (1.f / LQ_);
    }
    __syncthreads();
    if (tid < 128) {
      const int jc = tid & 31, m = tid >> 5;
      const float4* W4p = reinterpret_cast<const float4*>(Wm[m]) + jc;
      float4 ac = reinterpret_cast<const float4*>(bm[m])[jc];
      #pragma unroll 8
      for (int kk = 0; kk < 128; ++kk) {
        const float4 w = W4p[kk * 32];
        const float x = xe[0][kk];
        ac.x += x*w.x; ac.y += x*w.y; ac.z += x*w.z; ac.w += x*w.w;
      }
      *reinterpret_cast<float4*>(om[m] + ((size_t)b * 257) * 128 + 4 * jc) = ac;
    }
  }
}

// ---------------- edge multiplicity (verified round 1) -----------------------
__device__ __forceinline__ float cntf(int dnode, int s) {
  if (dnode == 256) return (s == 0 ? 1.f : 0.f) + (s == 255 ? 1.f : 0.f);
  float c = (s != dnode) ? 1.f : 0.f;          // semantic all-pairs (nodes 0..255)
  if (s == 0) c += 1.f;                        // query->segment
  if (s == dnode - 1) c += 2.f;                // qe chain + temporal h=1 fwd
  if (s == dnode + 1 && dnode <= 254) c += 1.f;// temporal h=1 bwd
  if (s == dnode - 2 && dnode >= 2) c += 1.f;  // temporal h=2 fwd
  if (s == dnode + 2 && dnode <= 253) c += 1.f;// temporal h=2 bwd
  return c;
}

// ---------------- k_attn4: register-P attention partials ---------------------
// grid (8 dtiles x32 dst, 8 stiles x32 s, 8 b) = 512 blocks, 256 thr.
// thread = (dd=tid>>3, h=tid&7): full P row in registers, no P LDS traffic.
__global__ __launch_bounds__(256) void k_attn4(
    const float* __restrict__ q, const float* __restrict__ k,
    const float* __restrict__ v,
    float* __restrict__ npart, float* __restrict__ dpart)
{
  __shared__ float Kl[32][128];
  __shared__ float Vl[32][128];
  const int d0 = blockIdx.x * 32;
  const int y  = blockIdx.y;
  const int b  = blockIdx.z;
  const int tid = threadIdx.x;
  const int base = b * 257;
  const int s0 = y * 32;
  {
    const float4* ksrc = reinterpret_cast<const float4*>(k + (size_t)(base + s0) * 128);
    const float4* vsrc = reinterpret_cast<const float4*>(v + (size_t)(base + s0) * 128);
    float4* kd = reinterpret_cast<float4*>(Kl);
    float4* vd = reinterpret_cast<float4*>(Vl);
    #pragma unroll
    for (int i = 0; i < 4; ++i) {
      kd[tid + i * 256] = ksrc[tid + i * 256];
      vd[tid + i * 256] = vsrc[tid + i * 256];
    }
  }
  const int dd = tid >> 3, h = tid & 7;
  const int dnode = d0 + dd + 1;
  const float* qrow = q + (size_t)(base + dnode) * 128 + h * 16;
  const float4 qq0 = *(const float4*)(qrow + 0);
  const float4 qq1 = *(const float4*)(qrow + 4);
  const float4 qq2 = *(const float4*)(qrow + 8);
  const float4 qq3 = *(const float4*)(qrow + 12);
  __syncthreads();

  float p[32];
  float den = 0.f;
  #pragma unroll
  for (int s = 0; s < 32; ++s) {
    const float* krow = &Kl[s][h * 16];
    const float4 k0 = *(const float4*)(krow + 0);
    const float4 k1 = *(const float4*)(krow + 4);
    const float4 k2 = *(const float4*)(krow + 8);
    const float4 k3 = *(const float4*)(krow + 12);
    float dt = qq0.x*k0.x + qq0.y*k0.y + qq0.z*k0.z + qq0.w*k0.w
             + qq1.x*k1.x + qq1.y*k1.y + qq1.z*k1.z + qq1.w*k1.w
             + qq2.x*k2.x + qq2.y*k2.y + qq2.z*k2.z + qq2.w*k2.w
             + qq3.x*k3.x + qq3.y*k3.y + qq3.z*k3.z + qq3.w*k3.w;
    const float c = cntf(dnode, s0 + s);
    p[s] = c * __expf(dt * 0.25f);
    den += p[s];
  }
  float4 o0 = {0,0,0,0}, o1 = {0,0,0,0}, o2 = {0,0,0,0}, o3 = {0,0,0,0};
  #pragma unroll
  for (int s = 0; s < 32; ++s) {
    const float* vrow = &Vl[s][h * 16];
    const float4 v0 = *(const float4*)(vrow + 0);
    const float4 v1 = *(const float4*)(vrow + 4);
    const float4 v2 = *(const float4*)(vrow + 8);
    const float4 v3 = *(const float4*)(vrow + 12);
    const float pw = p[s];
    o0.x += pw*v0.x; o0.y += pw*v0.y; o0.z += pw*v0.z; o0.w += pw*v0.w;
    o1.x += pw*v1.x; o1.y += pw*v1.y; o1.z += pw*v1.z; o1.w += pw*v1.w;
    o2.x += pw*v2.x; o2.y += pw*v2.y; o2.z += pw*v2.z; o2.w += pw*v2.w;
    o3.x += pw*v3.x; o3.y += pw*v3.y; o3.z += pw*v3.z; o3.w += pw*v3.w;
  }
  const size_t pb = ((size_t)y * 8 + b) * 256 + d0;
  float* np = npart + (pb + dd) * 128 + h * 16;
  *reinterpret_cast<float4*>(np + 0)  = o0;
  *reinterpret_cast<float4*>(np + 4)  = o1;
  *reinterpret_cast<float4*>(np + 8)  = o2;
  *reinterpret_cast<float4*>(np + 12) = o3;
  dpart[(pb + dd) * 8 + h] = den;
}

// ---------------- k_red: combine 8 partials + skip + start/end logits --------
__global__ __launch_bounds__(256) void k_red(
    const float* __restrict__ npart, const float* __restrict__ dpart,
    const float* __restrict__ sk,
    const float* __restrict__ W_start, const float* __restrict__ b_start,
    const float* __restrict__ W_end, const float* __restrict__ b_end,
    float* __restrict__ out)
{
  __shared__ float red[16][2][2];
  const int d0 = blockIdx.x * 16;
  const int b = blockIdx.y;
  const int tid = threadIdx.x;
  const int base = b * 257;
  const int jB = tid & 127, shB = tid >> 7;
  const int hB = jB >> 4;
  const float wst = W_start[jB], wen = W_end[jB];
  #pragma unroll
  for (int dd8 = 0; dd8 < 8; ++dd8) {
    const int dd = shB * 8 + dd8;
    const int dst = d0 + dd;
    float num = 0.f, den = 0.f;
    #pragma unroll
    for (int y = 0; y < 8; ++y) {
      const size_t pb = ((size_t)y * 8 + b) * 256 + dst;
      num += npart[pb * 128 + jB];
      den += dpart[pb * 8 + hB];
    }
    const float o = num / (den + 1e-16f) + sk[(size_t)(base + dst + 1) * 128 + jB];
    float psum = o * wst, pesum = o * wen;
    #pragma unroll
    for (int off = 1; off < 64; off <<= 1) {
      psum += __shfl_xor(psum, off);
      pesum += __shfl_xor(pesum, off);
    }
    if ((tid & 63) == 0) { red[dd][jB >> 6][0] = psum; red[dd][jB >> 6][1] = pesum; }
  }
  __syncthreads();
  if (tid < 16) {
    out[b * 256 + d0 + tid]        = red[tid][0][0] + red[tid][1][0] + b_start[0];
    out[2048 + b * 256 + d0 + tid] = red[tid][0][1] + red[tid][1][1] + b_end[0];
  }
}

extern "C" void kernel_launch(void* const* d_in, const int* in_sizes, int n_in,
                              void* d_out, int out_size, void* d_ws, size_t ws_size,
                              hipStream_t stream) {
  const int*   word_ids = (const int*)d_in[0];
  const int*   char_ids = (const int*)d_in[1];
  const float* video    = (const float*)d_in[2];
  const float* v_mask   = (const float*)d_in[3];
  const float* q_mask   = (const float*)d_in[4];
  const float* word_emb = (const float*)d_in[5];
  const float* char_emb = (const float*)d_in[6];
  const float* W_embed  = (const float*)d_in[7];
  const float* b_embed  = (const float*)d_in[8];
  const float* W_vproj  = (const float*)d_in[9];
  const float* b_vproj  = (const float*)d_in[10];
  const float* W_enc    = (const float*)d_in[11];
  const float* b_enc    = (const float*)d_in[12];
  const float* Wq       = (const float*)d_in[13];
  const float* bq       = (const float*)d_in[14];
  const float* Wk       = (const float*)d_in[15];
  const float* bk       = (const float*)d_in[16];
  const float* Wv       = (const float*)d_in[17];
  const float* bv       = (const float*)d_in[18];
  const float* Wskip    = (const float*)d_in[19];
  const float* bskip    = (const float*)d_in[20];
  const float* W_start  = (const float*)d_in[21];
  const float* b_start  = (const float*)d_in[22];
  const float* W_end    = (const float*)d_in[23];
  const float* b_end    = (const float*)d_in[24];

  float* xf   = (float*)d_ws;           // slot kept for layout stability (unused)
  float* q    = xf + NN_ * DIM_;
  float* k    = q  + NN_ * DIM_;
  float* v    = k  + NN_ * DIM_;
  float* sk   = v  + NN_ * DIM_;
  float* part = sk + NN_ * DIM_;        // 8 * 2048 * 128 floats = 8 MB
  float* eq   = part + 8 * 2048 * 128;  // 160 * 128 floats
  float* dpart = eq + 160 * 128;        // 8*8*256*8 floats
  float* npart = part;                  // alias: part dead after kBR3

  hipLaunchKernelGGL(kAQ, dim3(1184), dim3(256), 0, stream,
    video, W_vproj, word_ids, char_ids, word_emb, char_emb,
    W_embed, b_embed, W_enc, b_enc, q_mask, part, eq);
  hipLaunchKernelGGL(kBR3, dim3(264), dim3(256), 0, stream,
    part, b_vproj, W_enc, b_enc, v_mask, eq,
    Wq, bq, Wk, bk, Wv, bv, Wskip, bskip, q, k, v, sk);
  hipLaunchKernelGGL(k_attn4, dim3(8, 8, 8), dim3(256), 0, stream,
    q, k, v, npart, dpart);
  hipLaunchKernelGGL(k_red, dim3(16, 8), dim3(256), 0, stream,
    npart, dpart, sk, W_start, b_start, W_end, b_end, (float*)d_out);
}

// Round 7
// 76.422 us; speedup vs baseline: 1.1404x; 1.1404x over previous
//
#include <hip/hip_runtime.h>
#include <hip/hip_bf16.h>
#include <math.h>

#define B_ 8
#define T_ 256
#define LQ_ 20
#define LC_ 10
#define DIM_ 128
#define N_ 257            // T+1
#define NN_ (B_*N_)       // 2056

// ---------------- kAQ: video @ W_vproj split-K  ∪  query per-(b,lq) rows -----
__global__ __launch_bounds__(256) void kAQ(
    const float* __restrict__ video, const float* __restrict__ Wv,
    const int* __restrict__ word_ids, const int* __restrict__ char_ids,
    const float* __restrict__ word_emb, const float* __restrict__ char_emb,
    const float* __restrict__ W_embed, const float* __restrict__ b_embed,
    const float* __restrict__ We, const float* __restrict__ be,
    const float* __restrict__ q_mask,
    float* __restrict__ part, float* __restrict__ eq)
{
  __shared__ float smem[16 * 128];
  const int blk = blockIdx.x, tid = threadIdx.x;
  if (blk < 1024) {
    float (*Vl)[128] = reinterpret_cast<float(*)[128]>(smem);
    const int rt = blk & 127, ks = blk >> 7;
    const int r0 = rt * 16;
    for (int idx4 = tid; idx4 < 512; idx4 += 256) {
      const int i = idx4 >> 5, f = idx4 & 31;
      reinterpret_cast<float4*>(&Vl[i][0])[f] =
        reinterpret_cast<const float4*>(video + (size_t)(r0 + i) * 1024 + ks * 128)[f];
    }
    __syncthreads();
    const int jc = tid & 31, rg = tid >> 5;
    const int ra = rg * 2, rb = ra + 1;
    const float4* W4 = reinterpret_cast<const float4*>(Wv + (size_t)ks * 128 * 128) + jc;
    float4 a0 = {0,0,0,0}, a1 = {0,0,0,0};
    #pragma unroll 8
    for (int k = 0; k < 128; ++k) {
      const float4 w = W4[k * 32];
      const float x0 = Vl[ra][k], x1 = Vl[rb][k];
      a0.x += x0*w.x; a0.y += x0*w.y; a0.z += x0*w.z; a0.w += x0*w.w;
      a1.x += x1*w.x; a1.y += x1*w.y; a1.z += x1*w.z; a1.w += x1*w.w;
    }
    *reinterpret_cast<float4*>(part + (((size_t)ks * 2048) + r0 + ra) * 128 + 4 * jc) = a0;
    *reinterpret_cast<float4*>(part + (((size_t)ks * 2048) + r0 + rb) * 128 + 4 * jc) = a1;
  } else {
    const int qi = blk - 1024;
    const int b = qi / 20, lq = qi - b * 20;
    float* emb = smem;            // [352]
    float* ps  = smem + 352;      // [2][128]
    float* hl  = smem + 608;      // [128]
    float* pe  = smem + 736;      // [2][128]
    const int wid = word_ids[b * LQ_ + lq];
    for (int m = tid; m < 300; m += 256) emb[m] = word_emb[(size_t)wid * 300 + m];
    if (tid < 50) {
      float s = 0.f;
      #pragma unroll
      for (int l = 0; l < 10; ++l) {
        const int cid = char_ids[(b * LQ_ + lq) * 10 + l];
        s += char_emb[cid * 50 + tid];
      }
      emb[300 + tid] = s * 0.1f;
    }
    __syncthreads();
    const int j = tid & 127, half = tid >> 7;
    float a = 0.f;
    const float* Wcol = W_embed + (size_t)(half * 175) * 128 + j;
    const float* eh = emb + half * 175;
    #pragma unroll 5
    for (int m = 0; m < 175; ++m) a += eh[m] * Wcol[(size_t)m * 128];
    ps[half * 128 + j] = a;
    __syncthreads();
    if (tid < 128) hl[tid] = ps[tid] + ps[128 + tid] + b_embed[tid];
    __syncthreads();
    float e = 0.f;
    #pragma unroll 8
    for (int kk = 0; kk < 64; ++kk)
      e += hl[half * 64 + kk] * We[(half * 64 + kk) * 128 + j];
    pe[half * 128 + j] = e;
    __syncthreads();
    if (tid < 128) {
      float ev = pe[tid] + pe[128 + tid] + be[tid];
      ev = fmaxf(ev, 0.f) * q_mask[b * LQ_ + lq];
      eq[(size_t)qi * 128 + tid] = ev;
    }
  }
}

// ---------------- kBR3: 8-row blocks: part-reduce + enc + fused projections --
__global__ __launch_bounds__(256) void kBR3(
    const float* __restrict__ part, const float* __restrict__ bvp,
    const float* __restrict__ We, const float* __restrict__ be,
    const float* __restrict__ vmask, const float* __restrict__ eq,
    const float* __restrict__ Wq, const float* __restrict__ bq,
    const float* __restrict__ Wk, const float* __restrict__ bk,
    const float* __restrict__ Wvv, const float* __restrict__ bval,
    const float* __restrict__ Ws, const float* __restrict__ bs,
    float* __restrict__ q, float* __restrict__ k,
    float* __restrict__ v, float* __restrict__ sk)
{
  __shared__ float h[8][128];
  __shared__ float xe[8][132];     // pad 132: bank-spread, 16B-aligned rows
  const int blk = blockIdx.x, tid = threadIdx.x;
  const float* Wm[4] = {Wq, Wk, Wvv, Ws};
  const float* bm[4] = {bq, bk, bval, bs};
  float* om[4] = {q, k, v, sk};
  if (blk < 256) {
    const int col = tid & 127, rh = tid >> 7;
    const int r0 = blk * 8;
    #pragma unroll
    for (int rr = 0; rr < 4; ++rr) {
      const int row = rr * 2 + rh;
      float s = bvp[col];
      #pragma unroll
      for (int ks = 0; ks < 8; ++ks)
        s += part[((size_t)ks * 2048 + r0 + row) * 128 + col];
      h[row][col] = s;
    }
    __syncthreads();
    const int jc = tid & 31, rg = tid >> 5;
    {
      const float4* We4 = reinterpret_cast<const float4*>(We) + jc;
      float4 a = reinterpret_cast<const float4*>(be)[jc];
      #pragma unroll 8
      for (int kk = 0; kk < 128; ++kk) {
        const float4 w = We4[kk * 32];
        const float x = h[rg][kk];
        a.x += x*w.x; a.y += x*w.y; a.z += x*w.z; a.w += x*w.w;
      }
      const float mk = vmask[r0 + rg];
      a.x = fmaxf(a.x, 0.f) * mk; a.y = fmaxf(a.y, 0.f) * mk;
      a.z = fmaxf(a.z, 0.f) * mk; a.w = fmaxf(a.w, 0.f) * mk;
      *reinterpret_cast<float4*>(&xe[rg][4 * jc]) = a;
    }
    __syncthreads();
    const int m = rg & 3, g = rg >> 2;
    const float4* W4p = reinterpret_cast<const float4*>(Wm[m]) + jc;
    const float4 bb = reinterpret_cast<const float4*>(bm[m])[jc];
    float4 ac0 = bb, ac1 = bb, ac2 = bb, ac3 = bb;
    #pragma unroll 4
    for (int kk = 0; kk < 128; ++kk) {
      const float4 w = W4p[kk * 32];
      const float x0 = xe[4*g+0][kk], x1 = xe[4*g+1][kk];
      const float x2 = xe[4*g+2][kk], x3 = xe[4*g+3][kk];
      ac0.x += x0*w.x; ac0.y += x0*w.y; ac0.z += x0*w.z; ac0.w += x0*w.w;
      ac1.x += x1*w.x; ac1.y += x1*w.y; ac1.z += x1*w.z; ac1.w += x1*w.w;
      ac2.x += x2*w.x; ac2.y += x2*w.y; ac2.z += x2*w.z; ac2.w += x2*w.w;
      ac3.x += x3*w.x; ac3.y += x3*w.y; ac3.z += x3*w.z; ac3.w += x3*w.w;
    }
    float4 acs[4] = {ac0, ac1, ac2, ac3};
    #pragma unroll
    for (int r = 0; r < 4; ++r) {
      const int vr = r0 + 4 * g + r;
      const int node = (vr >> 8) * 257 + 1 + (vr & 255);
      *reinterpret_cast<float4*>(om[m] + (size_t)node * 128 + 4 * jc) = acs[r];
    }
  } else {
    const int b = blk - 256;
    if (tid < 128) {
      float s = 0.f;
      #pragma unroll 4
      for (int lq = 0; lq < LQ_; ++lq) s += eq[((size_t)b * LQ_ + lq) * 128 + tid];
      xe[0][tid] = s * (1.f / LQ_);
    }
    __syncthreads();
    if (tid < 128) {
      const int jc = tid & 31, m = tid >> 5;
      const float4* W4p = reinterpret_cast<const float4*>(Wm[m]) + jc;
      float4 ac = reinterpret_cast<const float4*>(bm[m])[jc];
      #pragma unroll 8
      for (int kk = 0; kk < 128; ++kk) {
        const float4 w = W4p[kk * 32];
        const float x = xe[0][kk];
        ac.x += x*w.x; ac.y += x*w.y; ac.z += x*w.z; ac.w += x*w.w;
      }
      *reinterpret_cast<float4*>(om[m] + ((size_t)b * 257) * 128 + 4 * jc) = ac;
    }
  }
}

// ---------------- edge multiplicity (verified round 1) -----------------------
__device__ __forceinline__ float cntf(int dnode, int s) {
  if (dnode == 256) return (s == 0 ? 1.f : 0.f) + (s == 255 ? 1.f : 0.f);
  float c = (s != dnode) ? 1.f : 0.f;          // semantic all-pairs (nodes 0..255)
  if (s == 0) c += 1.f;                        // query->segment
  if (s == dnode - 1) c += 2.f;                // qe chain + temporal h=1 fwd
  if (s == dnode + 1 && dnode <= 254) c += 1.f;// temporal h=1 bwd
  if (s == dnode - 2 && dnode >= 2) c += 1.f;  // temporal h=2 fwd
  if (s == dnode + 2 && dnode <= 253) c += 1.f;// temporal h=2 bwd
  return c;
}

// ---------------- k_attn5: single-pass fused exp+PV, no P state --------------
// grid (8 dtiles x32 dst, 8 stiles x32 s, 8 b) = 512 blocks, 256 thr.
// thread = (dd=tid>>3, h=tid&7). den & o accumulate in the SAME s-loop:
// no P array -> ~80 live VGPRs, no spill (R5 failure was 256-VGPR scratch spill).
__global__ __launch_bounds__(256) void k_attn5(
    const float* __restrict__ q, const float* __restrict__ k,
    const float* __restrict__ v,
    float* __restrict__ npart, float* __restrict__ dpart)
{
  __shared__ float Kl[32][128];
  __shared__ float Vl[32][128];
  const int d0 = blockIdx.x * 32;
  const int y  = blockIdx.y;
  const int b  = blockIdx.z;
  const int tid = threadIdx.x;
  const int base = b * 257;
  const int s0 = y * 32;
  {
    const float4* ksrc = reinterpret_cast<const float4*>(k + (size_t)(base + s0) * 128);
    const float4* vsrc = reinterpret_cast<const float4*>(v + (size_t)(base + s0) * 128);
    float4* kd = reinterpret_cast<float4*>(Kl);
    float4* vd = reinterpret_cast<float4*>(Vl);
    #pragma unroll
    for (int i = 0; i < 4; ++i) {
      kd[tid + i * 256] = ksrc[tid + i * 256];
      vd[tid + i * 256] = vsrc[tid + i * 256];
    }
  }
  const int dd = tid >> 3, h = tid & 7;
  const int dnode = d0 + dd + 1;
  const float* qrow = q + (size_t)(base + dnode) * 128 + h * 16;
  const float4 qq0 = *(const float4*)(qrow + 0);
  const float4 qq1 = *(const float4*)(qrow + 4);
  const float4 qq2 = *(const float4*)(qrow + 8);
  const float4 qq3 = *(const float4*)(qrow + 12);
  __syncthreads();

  float den = 0.f;
  float4 o0 = {0,0,0,0}, o1 = {0,0,0,0}, o2 = {0,0,0,0}, o3 = {0,0,0,0};
  #pragma unroll 2
  for (int s = 0; s < 32; ++s) {
    const float* krow = &Kl[s][h * 16];
    const float4 k0 = *(const float4*)(krow + 0);
    const float4 k1 = *(const float4*)(krow + 4);
    const float4 k2 = *(const float4*)(krow + 8);
    const float4 k3 = *(const float4*)(krow + 12);
    float dt = qq0.x*k0.x + qq0.y*k0.y + qq0.z*k0.z + qq0.w*k0.w
             + qq1.x*k1.x + qq1.y*k1.y + qq1.z*k1.z + qq1.w*k1.w
             + qq2.x*k2.x + qq2.y*k2.y + qq2.z*k2.z + qq2.w*k2.w
             + qq3.x*k3.x + qq3.y*k3.y + qq3.z*k3.z + qq3.w*k3.w;
    const float c = cntf(dnode, s0 + s);
    const float pw = c * __expf(dt * 0.25f);
    den += pw;
    const float* vrow = &Vl[s][h * 16];
    const float4 v0 = *(const float4*)(vrow + 0);
    const float4 v1 = *(const float4*)(vrow + 4);
    const float4 v2 = *(const float4*)(vrow + 8);
    const float4 v3 = *(const float4*)(vrow + 12);
    o0.x += pw*v0.x; o0.y += pw*v0.y; o0.z += pw*v0.z; o0.w += pw*v0.w;
    o1.x += pw*v1.x; o1.y += pw*v1.y; o1.z += pw*v1.z; o1.w += pw*v1.w;
    o2.x += pw*v2.x; o2.y += pw*v2.y; o2.z += pw*v2.z; o2.w += pw*v2.w;
    o3.x += pw*v3.x; o3.y += pw*v3.y; o3.z += pw*v3.z; o3.w += pw*v3.w;
  }
  const size_t pb = ((size_t)y * 8 + b) * 256 + d0;
  float* np = npart + (pb + dd) * 128 + h * 16;
  *reinterpret_cast<float4*>(np + 0)  = o0;
  *reinterpret_cast<float4*>(np + 4)  = o1;
  *reinterpret_cast<float4*>(np + 8)  = o2;
  *reinterpret_cast<float4*>(np + 12) = o3;
  dpart[(pb + dd) * 8 + h] = den;
}

// ---------------- k_red: combine 8 partials + skip + start/end logits --------
__global__ __launch_bounds__(256) void k_red(
    const float* __restrict__ npart, const float* __restrict__ dpart,
    const float* __restrict__ sk,
    const float* __restrict__ W_start, const float* __restrict__ b_start,
    const float* __restrict__ W_end, const float* __restrict__ b_end,
    float* __restrict__ out)
{
  __shared__ float red[16][2][2];
  const int d0 = blockIdx.x * 16;
  const int b = blockIdx.y;
  const int tid = threadIdx.x;
  const int base = b * 257;
  const int jB = tid & 127, shB = tid >> 7;
  const int hB = jB >> 4;
  const float wst = W_start[jB], wen = W_end[jB];
  #pragma unroll
  for (int dd8 = 0; dd8 < 8; ++dd8) {
    const int dd = shB * 8 + dd8;
    const int dst = d0 + dd;
    float num = 0.f, den = 0.f;
    #pragma unroll
    for (int y = 0; y < 8; ++y) {
      const size_t pb = ((size_t)y * 8 + b) * 256 + dst;
      num += npart[pb * 128 + jB];
      den += dpart[pb * 8 + hB];
    }
    const float o = num / (den + 1e-16f) + sk[(size_t)(base + dst + 1) * 128 + jB];
    float psum = o * wst, pesum = o * wen;
    #pragma unroll
    for (int off = 1; off < 64; off <<= 1) {
      psum += __shfl_xor(psum, off);
      pesum += __shfl_xor(pesum, off);
    }
    if ((tid & 63) == 0) { red[dd][jB >> 6][0] = psum; red[dd][jB >> 6][1] = pesum; }
  }
  __syncthreads();
  if (tid < 16) {
    out[b * 256 + d0 + tid]        = red[tid][0][0] + red[tid][1][0] + b_start[0];
    out[2048 + b * 256 + d0 + tid] = red[tid][0][1] + red[tid][1][1] + b_end[0];
  }
}

extern "C" void kernel_launch(void* const* d_in, const int* in_sizes, int n_in,
                              void* d_out, int out_size, void* d_ws, size_t ws_size,
                              hipStream_t stream) {
  const int*   word_ids = (const int*)d_in[0];
  const int*   char_ids = (const int*)d_in[1];
  const float* video    = (const float*)d_in[2];
  const float* v_mask   = (const float*)d_in[3];
  const float* q_mask   = (const float*)d_in[4];
  const float* word_emb = (const float*)d_in[5];
  const float* char_emb = (const float*)d_in[6];
  const float* W_embed  = (const float*)d_in[7];
  const float* b_embed  = (const float*)d_in[8];
  const float* W_vproj  = (const float*)d_in[9];
  const float* b_vproj  = (const float*)d_in[10];
  const float* W_enc    = (const float*)d_in[11];
  const float* b_enc    = (const float*)d_in[12];
  const float* Wq       = (const float*)d_in[13];
  const float* bq       = (const float*)d_in[14];
  const float* Wk       = (const float*)d_in[15];
  const float* bk       = (const float*)d_in[16];
  const float* Wv       = (const float*)d_in[17];
  const float* bv       = (const float*)d_in[18];
  const float* Wskip    = (const float*)d_in[19];
  const float* bskip    = (const float*)d_in[20];
  const float* W_start  = (const float*)d_in[21];
  const float* b_start  = (const float*)d_in[22];
  const float* W_end    = (const float*)d_in[23];
  const float* b_end    = (const float*)d_in[24];

  float* xf   = (float*)d_ws;           // slot kept for layout stability (unused)
  float* q    = xf + NN_ * DIM_;
  float* k    = q  + NN_ * DIM_;
  float* v    = k  + NN_ * DIM_;
  float* sk   = v  + NN_ * DIM_;
  float* part = sk + NN_ * DIM_;        // 8 * 2048 * 128 floats = 8 MB
  float* eq   = part + 8 * 2048 * 128;  // 160 * 128 floats
  float* dpart = eq + 160 * 128;        // 8*8*256*8 floats
  float* npart = part;                  // alias: part dead after kBR3

  hipLaunchKernelGGL(kAQ, dim3(1184), dim3(256), 0, stream,
    video, W_vproj, word_ids, char_ids, word_emb, char_emb,
    W_embed, b_embed, W_enc, b_enc, q_mask, part, eq);
  hipLaunchKernelGGL(kBR3, dim3(264), dim3(256), 0, stream,
    part, b_vproj, W_enc, b_enc, v_mask, eq,
    Wq, bq, Wk, bk, Wv, bv, Wskip, bskip, q, k, v, sk);
  hipLaunchKernelGGL(k_attn5, dim3(8, 8, 8), dim3(256), 0, stream,
    q, k, v, npart, dpart);
  hipLaunchKernelGGL(k_red, dim3(16, 8), dim3(256), 0, stream,
    npart, dpart, sk, W_start, b_start, W_end, b_end, (float*)d_out);
}

// Round 8
// 68.670 us; speedup vs baseline: 1.2691x; 1.1129x over previous
//
#include <hip/hip_runtime.h>
#include <hip/hip_bf16.h>
#include <math.h>

#define B_ 8
#define T_ 256
#define LQ_ 20
#define LC_ 10
#define DIM_ 128
#define N_ 257            // T+1
#define NN_ (B_*N_)       // 2056

// ---------------- kNODE: full node pipeline, one kernel ----------------------
// blocks 0..159: query row qi -> eq[qi][128]
// blocks 160..415: 8 video rows: V@Wv (full K, in-block split-2) -> enc -> 4 projections
__global__ __launch_bounds__(256) void kNODE(
    const float* __restrict__ video, const float* __restrict__ Wv,
    const float* __restrict__ bvp,
    const float* __restrict__ We, const float* __restrict__ be,
    const float* __restrict__ vmask,
    const int* __restrict__ word_ids, const int* __restrict__ char_ids,
    const float* __restrict__ word_emb, const float* __restrict__ char_emb,
    const float* __restrict__ W_embed, const float* __restrict__ b_embed,
    const float* __restrict__ q_mask,
    const float* __restrict__ Wq, const float* __restrict__ bq,
    const float* __restrict__ Wk, const float* __restrict__ bk,
    const float* __restrict__ Wvv, const float* __restrict__ bval,
    const float* __restrict__ Ws, const float* __restrict__ bs,
    float* __restrict__ q, float* __restrict__ k,
    float* __restrict__ v, float* __restrict__ sk,
    float* __restrict__ eq)
{
  __shared__ float smem[8 * 1024];     // 32 KB: 8 video rows (or query scratch)
  __shared__ float ps2[2][8][128];     // k-split halves
  __shared__ float xe[8][132];         // encoded rows (pad 132)
  const int blk = blockIdx.x, tid = threadIdx.x;
  const float* Wm[4] = {Wq, Wk, Wvv, Ws};
  const float* bm[4] = {bq, bk, bval, bs};
  float* om[4] = {q, k, v, sk};

  if (blk < 160) {
    // ---- query row: eq[qi] ----
    const int qi = blk;
    const int b = qi / 20, lq = qi - b * 20;
    float* emb = smem;            // [352]
    float* ps  = smem + 352;      // [2][128]
    float* hl  = smem + 608;      // [128]
    float* pe  = smem + 736;      // [2][128]
    const int wid = word_ids[b * LQ_ + lq];
    for (int m = tid; m < 300; m += 256) emb[m] = word_emb[(size_t)wid * 300 + m];
    if (tid < 50) {
      float s = 0.f;
      #pragma unroll
      for (int l = 0; l < 10; ++l) {
        const int cid = char_ids[(b * LQ_ + lq) * 10 + l];
        s += char_emb[cid * 50 + tid];
      }
      emb[300 + tid] = s * 0.1f;
    }
    __syncthreads();
    const int j = tid & 127, half = tid >> 7;
    float a = 0.f;
    const float* Wcol = W_embed + (size_t)(half * 175) * 128 + j;
    const float* eh = emb + half * 175;
    #pragma unroll 5
    for (int m = 0; m < 175; ++m) a += eh[m] * Wcol[(size_t)m * 128];
    ps[half * 128 + j] = a;
    __syncthreads();
    if (tid < 128) hl[tid] = ps[tid] + ps[128 + tid] + b_embed[tid];
    __syncthreads();
    float e = 0.f;
    #pragma unroll 8
    for (int kk = 0; kk < 64; ++kk)
      e += hl[half * 64 + kk] * We[(half * 64 + kk) * 128 + j];
    pe[half * 128 + j] = e;
    __syncthreads();
    if (tid < 128) {
      float ev = pe[tid] + pe[128 + tid] + be[tid];
      ev = fmaxf(ev, 0.f) * q_mask[b * LQ_ + lq];
      eq[(size_t)qi * 128 + tid] = ev;
    }
  } else {
    // ---- video: rows r0..r0+7 ----
    const int r0 = (blk - 160) * 8;
    float (*Vl)[1024] = reinterpret_cast<float(*)[1024]>(smem);
    {
      const float4* src = reinterpret_cast<const float4*>(video + (size_t)r0 * 1024);
      float4* dst = reinterpret_cast<float4*>(smem);
      #pragma unroll
      for (int i = 0; i < 8; ++i) dst[tid + i * 256] = src[tid + i * 256];
    }
    __syncthreads();
    const int jc = tid & 31, rg = tid >> 5;
    {
      // V @ Wv, K=1024 split into two 512 halves; 2 rows x 4 cols per thread
      const int half = rg >> 2, rp = rg & 3;
      const int ra = rp * 2, rb = ra + 1;
      const float4* W4 = reinterpret_cast<const float4*>(Wv) + (size_t)half * 512 * 32 + jc;
      const float* va = &Vl[ra][half * 512];
      const float* vb = &Vl[rb][half * 512];
      float4 a0 = {0,0,0,0}, a1 = {0,0,0,0};
      #pragma unroll 8
      for (int kk = 0; kk < 512; ++kk) {
        const float4 w = W4[(size_t)kk * 32];
        const float x0 = va[kk], x1 = vb[kk];
        a0.x += x0*w.x; a0.y += x0*w.y; a0.z += x0*w.z; a0.w += x0*w.w;
        a1.x += x1*w.x; a1.y += x1*w.y; a1.z += x1*w.z; a1.w += x1*w.w;
      }
      *reinterpret_cast<float4*>(&ps2[half][ra][4 * jc]) = a0;
      *reinterpret_cast<float4*>(&ps2[half][rb][4 * jc]) = a1;
    }
    __syncthreads();
    // combine halves + bias -> hl (alias video LDS, video data dead)
    float* hl = smem;   // [8][128]
    {
      const float4 p0 = *reinterpret_cast<const float4*>(&ps2[0][rg][4 * jc]);
      const float4 p1 = *reinterpret_cast<const float4*>(&ps2[1][rg][4 * jc]);
      const float4 bb = reinterpret_cast<const float4*>(bvp)[jc];
      float4 hh;
      hh.x = p0.x + p1.x + bb.x; hh.y = p0.y + p1.y + bb.y;
      hh.z = p0.z + p1.z + bb.z; hh.w = p0.w + p1.w + bb.w;
      *reinterpret_cast<float4*>(&hl[rg * 128 + 4 * jc]) = hh;
    }
    __syncthreads();
    // enc: row rg, 4 cols
    {
      const float4* We4 = reinterpret_cast<const float4*>(We) + jc;
      float4 a = reinterpret_cast<const float4*>(be)[jc];
      const float* hr = &hl[rg * 128];
      #pragma unroll 8
      for (int kk = 0; kk < 128; ++kk) {
        const float4 w = We4[kk * 32];
        const float x = hr[kk];
        a.x += x*w.x; a.y += x*w.y; a.z += x*w.z; a.w += x*w.w;
      }
      const float mk = vmask[r0 + rg];
      a.x = fmaxf(a.x, 0.f) * mk; a.y = fmaxf(a.y, 0.f) * mk;
      a.z = fmaxf(a.z, 0.f) * mk; a.w = fmaxf(a.w, 0.f) * mk;
      *reinterpret_cast<float4*>(&xe[rg][4 * jc]) = a;
    }
    __syncthreads();
    // projections: m = rg&3, g = rg>>2 -> rows 4g..4g+3, 16 FMA per W-load
    {
      const int m = rg & 3, g = rg >> 2;
      const float4* W4p = reinterpret_cast<const float4*>(Wm[m]) + jc;
      const float4 bb = reinterpret_cast<const float4*>(bm[m])[jc];
      float4 ac0 = bb, ac1 = bb, ac2 = bb, ac3 = bb;
      #pragma unroll 4
      for (int kk = 0; kk < 128; ++kk) {
        const float4 w = W4p[kk * 32];
        const float x0 = xe[4*g+0][kk], x1 = xe[4*g+1][kk];
        const float x2 = xe[4*g+2][kk], x3 = xe[4*g+3][kk];
        ac0.x += x0*w.x; ac0.y += x0*w.y; ac0.z += x0*w.z; ac0.w += x0*w.w;
        ac1.x += x1*w.x; ac1.y += x1*w.y; ac1.z += x1*w.z; ac1.w += x1*w.w;
        ac2.x += x2*w.x; ac2.y += x2*w.y; ac2.z += x2*w.z; ac2.w += x2*w.w;
        ac3.x += x3*w.x; ac3.y += x3*w.y; ac3.z += x3*w.z; ac3.w += x3*w.w;
      }
      float4 acs[4] = {ac0, ac1, ac2, ac3};
      #pragma unroll
      for (int r = 0; r < 4; ++r) {
        const int vr = r0 + 4 * g + r;
        const int node = (vr >> 8) * 257 + 1 + (vr & 255);
        *reinterpret_cast<float4*>(om[m] + (size_t)node * 128 + 4 * jc) = acs[r];
      }
    }
  }
}

// ---------------- edge multiplicity (verified round 1) -----------------------
__device__ __forceinline__ float cntf(int dnode, int s) {
  if (dnode == 256) return (s == 0 ? 1.f : 0.f) + (s == 255 ? 1.f : 0.f);
  float c = (s != dnode) ? 1.f : 0.f;          // semantic all-pairs (nodes 0..255)
  if (s == 0) c += 1.f;                        // query->segment
  if (s == dnode - 1) c += 2.f;                // qe chain + temporal h=1 fwd
  if (s == dnode + 1 && dnode <= 254) c += 1.f;// temporal h=1 bwd
  if (s == dnode - 2 && dnode >= 2) c += 1.f;  // temporal h=2 fwd
  if (s == dnode + 2 && dnode <= 253) c += 1.f;// temporal h=2 bwd
  return c;
}

// ---------------- kATTN: single-pass fused exp+PV; y==0 recomputes node-0 K/V
// grid (8 dtiles x32 dst, 8 stiles x32 s, 8 b), 256 thr. thread=(dd,h).
__global__ __launch_bounds__(256) void kATTN(
    const float* __restrict__ q, const float* __restrict__ k,
    const float* __restrict__ v, const float* __restrict__ eq,
    const float* __restrict__ Wk, const float* __restrict__ bk,
    const float* __restrict__ Wvv, const float* __restrict__ bval,
    float* __restrict__ npart, float* __restrict__ dpart)
{
  __shared__ float Kl[32][128];
  __shared__ float Vl[32][128];
  __shared__ float m0[128];
  const int d0 = blockIdx.x * 32;
  const int y  = blockIdx.y;
  const int b  = blockIdx.z;
  const int tid = threadIdx.x;
  const int base = b * 257;
  const int s0 = y * 32;
  {
    const float4* ksrc = reinterpret_cast<const float4*>(k + (size_t)(base + s0) * 128);
    const float4* vsrc = reinterpret_cast<const float4*>(v + (size_t)(base + s0) * 128);
    float4* kd = reinterpret_cast<float4*>(Kl);
    float4* vd = reinterpret_cast<float4*>(Vl);
    #pragma unroll
    for (int i = 0; i < 4; ++i) {
      kd[tid + i * 256] = ksrc[tid + i * 256];
      vd[tid + i * 256] = vsrc[tid + i * 256];
    }
  }
  if (y == 0 && tid < 128) {           // eq mean for this batch (global reads only)
    float s = 0.f;
    #pragma unroll 4
    for (int lq = 0; lq < LQ_; ++lq) s += eq[((size_t)b * LQ_ + lq) * 128 + tid];
    m0[tid] = s * (1.f / LQ_);
  }
  const int dd = tid >> 3, h = tid & 7;
  const int dnode = d0 + dd + 1;
  const float* qrow = q + (size_t)(base + dnode) * 128 + h * 16;
  const float4 qq0 = *(const float4*)(qrow + 0);
  const float4 qq1 = *(const float4*)(qrow + 4);
  const float4 qq2 = *(const float4*)(qrow + 8);
  const float4 qq3 = *(const float4*)(qrow + 12);
  __syncthreads();
  if (y == 0) {                        // overwrite row 0 with node-0 K/V
    const int j = tid & 127, half = tid >> 7;
    const float* W = half ? Wvv : Wk;
    float acc = half ? bval[j] : bk[j];
    #pragma unroll 8
    for (int kk = 0; kk < 128; ++kk) acc += m0[kk] * W[kk * 128 + j];
    if (half) Vl[0][j] = acc; else Kl[0][j] = acc;
  }
  __syncthreads();

  float den = 0.f;
  float4 o0 = {0,0,0,0}, o1 = {0,0,0,0}, o2 = {0,0,0,0}, o3 = {0,0,0,0};
  #pragma unroll 2
  for (int s = 0; s < 32; ++s) {
    const float* krow = &Kl[s][h * 16];
    const float4 k0 = *(const float4*)(krow + 0);
    const float4 k1 = *(const float4*)(krow + 4);
    const float4 k2 = *(const float4*)(krow + 8);
    const float4 k3 = *(const float4*)(krow + 12);
    float dt = qq0.x*k0.x + qq0.y*k0.y + qq0.z*k0.z + qq0.w*k0.w
             + qq1.x*k1.x + qq1.y*k1.y + qq1.z*k1.z + qq1.w*k1.w
             + qq2.x*k2.x + qq2.y*k2.y + qq2.z*k2.z + qq2.w*k2.w
             + qq3.x*k3.x + qq3.y*k3.y + qq3.z*k3.z + qq3.w*k3.w;
    const float c = cntf(dnode, s0 + s);
    const float pw = c * __expf(dt * 0.25f);
    den += pw;
    const float* vrow = &Vl[s][h * 16];
    const float4 v0 = *(const float4*)(vrow + 0);
    const float4 v1 = *(const float4*)(vrow + 4);
    const float4 v2 = *(const float4*)(vrow + 8);
    const float4 v3 = *(const float4*)(vrow + 12);
    o0.x += pw*v0.x; o0.y += pw*v0.y; o0.z += pw*v0.z; o0.w += pw*v0.w;
    o1.x += pw*v1.x; o1.y += pw*v1.y; o1.z += pw*v1.z; o1.w += pw*v1.w;
    o2.x += pw*v2.x; o2.y += pw*v2.y; o2.z += pw*v2.z; o2.w += pw*v2.w;
    o3.x += pw*v3.x; o3.y += pw*v3.y; o3.z += pw*v3.z; o3.w += pw*v3.w;
  }
  const size_t pb = ((size_t)y * 8 + b) * 256 + d0;
  float* np = npart + (pb + dd) * 128 + h * 16;
  *reinterpret_cast<float4*>(np + 0)  = o0;
  *reinterpret_cast<float4*>(np + 4)  = o1;
  *reinterpret_cast<float4*>(np + 8)  = o2;
  *reinterpret_cast<float4*>(np + 12) = o3;
  dpart[(pb + dd) * 8 + h] = den;
}

// ---------------- k_red: combine 8 partials + skip + start/end logits --------
__global__ __launch_bounds__(256) void k_red(
    const float* __restrict__ npart, const float* __restrict__ dpart,
    const float* __restrict__ sk,
    const float* __restrict__ W_start, const float* __restrict__ b_start,
    const float* __restrict__ W_end, const float* __restrict__ b_end,
    float* __restrict__ out)
{
  __shared__ float red[16][2][2];
  const int d0 = blockIdx.x * 16;
  const int b = blockIdx.y;
  const int tid = threadIdx.x;
  const int base = b * 257;
  const int jB = tid & 127, shB = tid >> 7;
  const int hB = jB >> 4;
  const float wst = W_start[jB], wen = W_end[jB];
  #pragma unroll
  for (int dd8 = 0; dd8 < 8; ++dd8) {
    const int dd = shB * 8 + dd8;
    const int dst = d0 + dd;
    float num = 0.f, den = 0.f;
    #pragma unroll
    for (int y = 0; y < 8; ++y) {
      const size_t pb = ((size_t)y * 8 + b) * 256 + dst;
      num += npart[pb * 128 + jB];
      den += dpart[pb * 8 + hB];
    }
    const float o = num / (den + 1e-16f) + sk[(size_t)(base + dst + 1) * 128 + jB];
    float psum = o * wst, pesum = o * wen;
    #pragma unroll
    for (int off = 1; off < 64; off <<= 1) {
      psum += __shfl_xor(psum, off);
      pesum += __shfl_xor(pesum, off);
    }
    if ((tid & 63) == 0) { red[dd][jB >> 6][0] = psum; red[dd][jB >> 6][1] = pesum; }
  }
  __syncthreads();
  if (tid < 16) {
    out[b * 256 + d0 + tid]        = red[tid][0][0] + red[tid][1][0] + b_start[0];
    out[2048 + b * 256 + d0 + tid] = red[tid][0][1] + red[tid][1][1] + b_end[0];
  }
}

extern "C" void kernel_launch(void* const* d_in, const int* in_sizes, int n_in,
                              void* d_out, int out_size, void* d_ws, size_t ws_size,
                              hipStream_t stream) {
  const int*   word_ids = (const int*)d_in[0];
  const int*   char_ids = (const int*)d_in[1];
  const float* video    = (const float*)d_in[2];
  const float* v_mask   = (const float*)d_in[3];
  const float* q_mask   = (const float*)d_in[4];
  const float* word_emb = (const float*)d_in[5];
  const float* char_emb = (const float*)d_in[6];
  const float* W_embed  = (const float*)d_in[7];
  const float* b_embed  = (const float*)d_in[8];
  const float* W_vproj  = (const float*)d_in[9];
  const float* b_vproj  = (const float*)d_in[10];
  const float* W_enc    = (const float*)d_in[11];
  const float* b_enc    = (const float*)d_in[12];
  const float* Wq       = (const float*)d_in[13];
  const float* bq       = (const float*)d_in[14];
  const float* Wk       = (const float*)d_in[15];
  const float* bk       = (const float*)d_in[16];
  const float* Wv       = (const float*)d_in[17];
  const float* bv       = (const float*)d_in[18];
  const float* Wskip    = (const float*)d_in[19];
  const float* bskip    = (const float*)d_in[20];
  const float* W_start  = (const float*)d_in[21];
  const float* b_start  = (const float*)d_in[22];
  const float* W_end    = (const float*)d_in[23];
  const float* b_end    = (const float*)d_in[24];

  float* q     = (float*)d_ws;
  float* k     = q  + NN_ * DIM_;
  float* v     = k  + NN_ * DIM_;
  float* sk    = v  + NN_ * DIM_;
  float* eq    = sk + NN_ * DIM_;               // 160*128
  float* npart = eq + 160 * 128;                // 8*8*256*128 = 2M floats
  float* dpart = npart + (size_t)8 * 8 * 256 * 128;  // 8*8*256*8

  hipLaunchKernelGGL(kNODE, dim3(416), dim3(256), 0, stream,
    video, W_vproj, b_vproj, W_enc, b_enc, v_mask,
    word_ids, char_ids, word_emb, char_emb, W_embed, b_embed, q_mask,
    Wq, bq, Wk, bk, Wv, bv, Wskip, bskip, q, k, v, sk, eq);
  hipLaunchKernelGGL(kATTN, dim3(8, 8, 8), dim3(256), 0, stream,
    q, k, v, eq, Wk, bk, Wv, bv, npart, dpart);
  hipLaunchKernelGGL(k_red, dim3(16, 8), dim3(256), 0, stream,
    npart, dpart, sk, W_start, b_start, W_end, b_end, (float*)d_out);
}